// Round 2
// baseline (389.107 us; speedup 1.0000x reference)
//
#include <hip/hip_runtime.h>
#include <hip/hip_bf16.h>
#include <cmath>

#define D_MODEL 1024
#define NHEADS 16
#define HDIM 64
#define BATCH 2
#define SEQ 2048
#define MROWS (BATCH*SEQ)   // 4096
#define KDIM 1024
#define NB 512              // grid size; 2 blocks/CU co-resident (256 CUs)

typedef unsigned short ushort_t;
typedef unsigned int uint32;
typedef __attribute__((ext_vector_type(8))) short short8;
typedef __attribute__((ext_vector_type(4))) short short4b;
typedef __attribute__((ext_vector_type(4))) float floatx4;

#define QSCALE 0.1803368801111204f   /* 0.125 * log2(e): scores land in exp2 domain */
#define EXP2F(x) __builtin_amdgcn_exp2f(x)

__device__ __forceinline__ ushort_t f2bf(float x) {
    union { float f; uint32 u; } v; v.f = x;
    uint32 r = v.u + 0x7FFFu + ((v.u >> 16) & 1u);
    return (ushort_t)(r >> 16);
}

__device__ __forceinline__ uint32 pkbf(float a, float b) {
    union { __hip_bfloat162 h2; uint32 u; } v;
    v.h2 = __float22bfloat162_rn(make_float2(a, b));
    return v.u;
}

__device__ __forceinline__ void glds16(const void* g, void* l) {
    __builtin_amdgcn_global_load_lds(
        (const __attribute__((address_space(1))) void*)g,
        (__attribute__((address_space(3))) void*)l, 16, 0, 0);
}

// Device-scope grid barrier (sense via monotonically increasing generation).
// __threadfence() at AGENT scope emits the L2 writeback (writer side) /
// invalidate (reader side) needed across non-coherent XCD L2s -- this
// replaces the implicit cache ops at kernel-dispatch boundaries.
__device__ __forceinline__ void grid_sync(unsigned* bar) {
    __syncthreads();                       // all block stores at vmcnt(0) -> in L2
    if (threadIdx.x == 0) {
        __threadfence();                   // L2 writeback, device scope
        unsigned g = __hip_atomic_load(&bar[1], __ATOMIC_RELAXED, __HIP_MEMORY_SCOPE_AGENT);
        unsigned old = __hip_atomic_fetch_add(&bar[0], 1u, __ATOMIC_ACQ_REL, __HIP_MEMORY_SCOPE_AGENT);
        if (old == NB - 1u) {              // last arriver: reset count, flip gen
            __hip_atomic_store(&bar[0], 0u, __ATOMIC_RELAXED, __HIP_MEMORY_SCOPE_AGENT);
            __hip_atomic_fetch_add(&bar[1], 1u, __ATOMIC_RELEASE, __HIP_MEMORY_SCOPE_AGENT);
        } else {
            while (__hip_atomic_load(&bar[1], __ATOMIC_RELAXED, __HIP_MEMORY_SCOPE_AGENT) == g)
                __builtin_amdgcn_s_sleep(8);
        }
        __threadfence();                   // L1/L2 invalidate before readers proceed
    }
    __syncthreads();
}

// workspace is poisoned between iterations -> barrier state must be re-zeroed
// inside the timed sequence each run.
__global__ void bar_init(unsigned* bar) {
    if (threadIdx.x < 2) bar[threadIdx.x] = 0u;
}

// ================= fused pipeline: cvt -> QKV GEMM -> attention -> out-proj ==============
__global__ __launch_bounds__(256, 2)
void mega(const float* __restrict__ x,
          const float* __restrict__ Wq, const float* __restrict__ bq,
          const float* __restrict__ Wk, const float* __restrict__ bk,
          const float* __restrict__ Wv, const float* __restrict__ bv,
          const float* __restrict__ Wo, const float* __restrict__ bo,
          ushort_t* __restrict__ xb, ushort_t* __restrict__ WtQKV,
          ushort_t* __restrict__ WtO, ushort_t* __restrict__ Qb,
          ushort_t* __restrict__ Kb, ushort_t* __restrict__ Vb,
          ushort_t* __restrict__ Hb, float* __restrict__ Cf,
          unsigned* __restrict__ bar)
{
    __shared__ __align__(16) float smemf[16640];   // 65 KB union across phases

    const int tid = threadIdx.x;
    const int blk = blockIdx.x;
    const int w = tid >> 6, lane = tid & 63;
    const int quad = lane >> 4, col = lane & 15;
    const floatx4 zero = {0.f, 0.f, 0.f, 0.f};

    // ---------------- Phase A1: x f32 -> bf16, 8192 elems/block ----------------
    {
        size_t b0i = (size_t)blk * 8192 + tid * 4;
        #pragma unroll
        for (int l = 0; l < 8; ++l) {
            size_t i = b0i + (size_t)l * 1024;
            float4 v = *(const float4*)(x + i);
            uint2 o;
            o.x = pkbf(v.x, v.y);
            o.y = pkbf(v.z, v.w);
            *(uint2*)(xb + i) = o;
        }
    }
    // ---------------- Phase A2: W transpose + cvt, 2x 64x64 tiles/block ----------------
    {
        ushort_t* tl = (ushort_t*)smemf;   // [64][68] bf16, stride 68 keeps 8B-aligned rows
        #pragma unroll 1
        for (int r = 0; r < 2; ++r) {
            int tt = blk * 2 + r;                     // 0..1023 = 4 matrices x 256 tiles
            int z = tt >> 8, ti = tt & 255;
            int tk = (ti & 15) * 64, tn = (ti >> 4) * 64;
            const float* W = (z == 0) ? Wq : (z == 1) ? Wk : (z == 2) ? Wv : Wo;
            ushort_t* out = (z < 3) ? (WtQKV + (size_t)z * 1048576) : WtO;
            __syncthreads();
            #pragma unroll
            for (int j = 0; j < 4; ++j) {
                int fid = j * 256 + tid;
                int kl = fid >> 4, c4 = fid & 15;
                float4 v = *(const float4*)(W + (size_t)(tk + kl) * 1024 + tn + c4 * 4);
                ushort4 u;
                u.x = f2bf(v.x); u.y = f2bf(v.y); u.z = f2bf(v.z); u.w = f2bf(v.w);
                *(ushort4*)(tl + kl * 68 + c4 * 4) = u;
            }
            __syncthreads();
            #pragma unroll
            for (int j = 0; j < 4; ++j) {
                int sid = j * 256 + tid;
                int nl = sid >> 4, k0 = (sid & 15) * 4;
                ushort4 u;
                u.x = tl[(k0 + 0) * 68 + nl];
                u.y = tl[(k0 + 1) * 68 + nl];
                u.z = tl[(k0 + 2) * 68 + nl];
                u.w = tl[(k0 + 3) * 68 + nl];
                *(ushort4*)(out + (size_t)(tn + nl) * 1024 + tk + k0) = u;
            }
        }
    }

    grid_sync(bar);

    // ---------------- Phase B: QKV GEMM, block tile 128x192 (512 blocks exact) -------
    // 4 waves, wave tile 64x96; same glds16 staging + XOR-chunk swizzle as proven R11.
    {
        ushort_t* As = (ushort_t*)smemf;            // [128][64] chunked, 16 KB
        ushort_t* Bs = (ushort_t*)smemf + 8192;     // [192][64] chunked, 24 KB
        const int bm = blk >> 4, bn = blk & 15;
        const int m0 = bm * 128, n0 = bn * 192;
        const int wm = w >> 1, wn = w & 1;

        floatx4 acc[4][6];
        #pragma unroll
        for (int i = 0; i < 4; ++i)
            #pragma unroll
            for (int j = 0; j < 6; ++j) acc[i][j] = zero;

        #pragma unroll 1
        for (int k0 = 0; k0 < KDIM; k0 += 64) {
            #pragma unroll
            for (int i = 0; i < 4; ++i) {
                int c = i * 256 + tid;
                int row = c >> 3;
                int kc = (c & 7) ^ (row & 7);
                glds16(xb + (size_t)(m0 + row) * KDIM + k0 + kc * 8, As + (i * 256 + w * 64) * 8);
            }
            #pragma unroll
            for (int i = 0; i < 6; ++i) {
                int c = i * 256 + tid;
                int row = c >> 3;
                int kc = (c & 7) ^ (row & 7);
                glds16(WtQKV + (size_t)(n0 + row) * KDIM + k0 + kc * 8, Bs + (i * 256 + w * 64) * 8);
            }
            __syncthreads();
            #pragma unroll
            for (int ks = 0; ks < 2; ++ks) {
                short8 af[4], bfr[6];
                const int kc = ks * 4 + quad;
                #pragma unroll
                for (int mt = 0; mt < 4; ++mt) {
                    int r = wm * 64 + mt * 16 + col;
                    af[mt] = *(const short8*)(As + ((size_t)r * 8 + (kc ^ (r & 7))) * 8);
                }
                #pragma unroll
                for (int nt = 0; nt < 6; ++nt) {
                    int r = wn * 96 + nt * 16 + col;
                    bfr[nt] = *(const short8*)(Bs + ((size_t)r * 8 + (kc ^ (r & 7))) * 8);
                }
                #pragma unroll
                for (int mt = 0; mt < 4; ++mt)
                    #pragma unroll
                    for (int nt = 0; nt < 6; ++nt)
                        acc[mt][nt] = __builtin_amdgcn_mfma_f32_16x16x32_bf16(
                            af[mt], bfr[nt], acc[mt][nt], 0, 0, 0);
            }
            __syncthreads();
        }

        // epilogue: which-output resolved per 16-col fragment (192-wide tiles cross Q/K/V)
        #pragma unroll
        for (int mt = 0; mt < 4; ++mt)
            #pragma unroll
            for (int nt = 0; nt < 6; ++nt) {
                int nbase = n0 + wn * 96 + nt * 16;
                int which = nbase >> 10;
                int nn = (nbase & 1023) + col;
                int h = nn >> 6, d = nn & 63;
                if (which == 0) {
                    float bb = bq[nn];
                    #pragma unroll
                    for (int r = 0; r < 4; ++r) {
                        int m = m0 + wm * 64 + mt * 16 + quad * 4 + r;
                        int b = m >> 11, s = m & 2047;
                        Qb[((size_t)(b * NHEADS + h) * SEQ + s) * HDIM + d] =
                            f2bf((acc[mt][nt][r] + bb) * QSCALE);
                    }
                } else if (which == 1) {
                    float bb = bk[nn];
                    #pragma unroll
                    for (int r = 0; r < 4; ++r) {
                        int m = m0 + wm * 64 + mt * 16 + quad * 4 + r;
                        int b = m >> 11, s = m & 2047;
                        Kb[((size_t)(b * NHEADS + h) * SEQ + s) * HDIM + d] =
                            f2bf(acc[mt][nt][r] + bb);
                    }
                } else {
                    float bb = bv[nn];
                    int mb = m0 + wm * 64 + mt * 16 + quad * 4;
                    int b = mb >> 11, s = mb & 2047;
                    uint2 pw;
                    pw.x = pkbf(acc[mt][nt][0] + bb, acc[mt][nt][1] + bb);
                    pw.y = pkbf(acc[mt][nt][2] + bb, acc[mt][nt][3] + bb);
                    *(uint2*)(Vb + ((size_t)(b * NHEADS + h) * HDIM + d) * SEQ + s) = pw;
                }
            }
    }

    grid_sync(bar);

    // ---------------- Phase C: flash causal attention (v8 kpos-split, verbatim) ------
    {
        ushort_t* Qs  = (ushort_t*)smemf;                      // [64][64]
        ushort_t* Ksm = (ushort_t*)(smemf + 2048);             // [2][64*64]
        ushort_t* Vsm = (ushort_t*)(smemf + 6144);             // [2][64*64]
        float* Ored = smemf;                                   // [4][64q][64d] swizzled
        float* Lred = smemf + 16384;                           // [4][64]

        const int bh = (blk & 7) * 4 + ((blk >> 3) & 3);  // XCD-grouped
        const int pair = blk >> 5;                        // 0..15
        const size_t base = (size_t)bh * SEQ * HDIM;
        const ushort_t* Kp = Kb + base;
        const ushort_t* Vp = Vb + base;
        const int bi = bh >> 4, hi = bh & 15;

        const int c0 = (w * 2 + 0) * 64 + lane;
        const int c1 = (w * 2 + 1) * 64 + lane;
        const int r0 = c0 >> 3, o0 = ((c0 & 7) ^ (r0 & 7)) * 8;
        const int r1 = c1 >> 3, o1 = ((c1 & 7) ^ (r1 & 7)) * 8;

        const int rk = w * 16 + col;          // wave's K row (kpos slice base + col)

        #pragma unroll 1
        for (int pi = 0; pi < 2; ++pi) {
            const int qt = pi ? pair : 31 - pair;
            const int q0 = qt * 64;
            const int ntk = qt + 1;

            __syncthreads();     // previous q-tile's epilogue readers of Ored done
            #pragma unroll
            for (int i = 0; i < 2; ++i) {
                int c = (w * 2 + i) * 64 + lane;
                int row = c >> 3, kc = (c & 7) ^ (row & 7);
                glds16(Qb + base + (size_t)(q0 + row) * HDIM + kc * 8, Qs + (w * 2 + i) * 512);
            }
            glds16(Kp + (size_t)r0 * HDIM + o0, Ksm + (w * 2 + 0) * 512);
            glds16(Kp + (size_t)r1 * HDIM + o1, Ksm + (w * 2 + 1) * 512);
            glds16(Vp + (size_t)r0 * SEQ + o0,  Vsm + (w * 2 + 0) * 512);
            glds16(Vp + (size_t)r1 * SEQ + o1,  Vsm + (w * 2 + 1) * 512);
            __syncthreads();     // Qs + buf0 ready

            short8 qf[4][2];
            #pragma unroll
            for (int qb2 = 0; qb2 < 4; ++qb2)
                #pragma unroll
                for (int ks = 0; ks < 2; ++ks) {
                    int rq = qb2 * 16 + col;
                    int kc = ks * 4 + quad;
                    qf[qb2][ks] = *(const short8*)(Qs + ((size_t)rq * 8 + (kc ^ (rq & 7))) * 8);
                }

            floatx4 o_[4][4];
            #pragma unroll
            for (int i = 0; i < 4; ++i)
                #pragma unroll
                for (int j = 0; j < 4; ++j) o_[i][j] = zero;
            float lq[4] = {0.f, 0.f, 0.f, 0.f};

            #pragma unroll 1
            for (int t = 0; t < ntk; ++t) {
                const ushort_t* Kcur = Ksm + (t & 1) * 4096;
                const ushort_t* Vcur = Vsm + (t & 1) * 4096;
                if (t + 1 < ntk) {
                    const int k0n = (t + 1) * 64;
                    ushort_t* Kn = Ksm + ((t + 1) & 1) * 4096;
                    ushort_t* Vn = Vsm + ((t + 1) & 1) * 4096;
                    glds16(Kp + (size_t)(k0n + r0) * HDIM + o0, Kn + (w * 2 + 0) * 512);
                    glds16(Kp + (size_t)(k0n + r1) * HDIM + o1, Kn + (w * 2 + 1) * 512);
                    glds16(Vp + (size_t)r0 * SEQ + k0n + o0,    Vn + (w * 2 + 0) * 512);
                    glds16(Vp + (size_t)r1 * SEQ + k0n + o1,    Vn + (w * 2 + 1) * 512);
                }

                floatx4 sc[4];
                #pragma unroll
                for (int qb2 = 0; qb2 < 4; ++qb2) sc[qb2] = zero;
                #pragma unroll
                for (int ks = 0; ks < 2; ++ks) {
                    const int kc = ks * 4 + quad;
                    short8 ak = *(const short8*)(Kcur + ((size_t)rk * 8 + (kc ^ (rk & 7))) * 8);
                    #pragma unroll
                    for (int qb2 = 0; qb2 < 4; ++qb2)
                        sc[qb2] = __builtin_amdgcn_mfma_f32_16x16x32_bf16(
                            ak, qf[qb2][ks], sc[qb2], 0, 0, 0);
                }

                if (t == ntk - 1) {
                    #pragma unroll
                    for (int qb2 = 0; qb2 < 4; ++qb2)
                        #pragma unroll
                        for (int r = 0; r < 4; ++r)
                            if (w * 16 + quad * 4 + r > qb2 * 16 + col) sc[qb2][r] = -INFINITY;
                }

                short4b bp[4];
                #pragma unroll
                for (int qb2 = 0; qb2 < 4; ++qb2) {
                    float p0 = EXP2F(sc[qb2][0]);
                    float p1 = EXP2F(sc[qb2][1]);
                    float p2 = EXP2F(sc[qb2][2]);
                    float p3 = EXP2F(sc[qb2][3]);
                    lq[qb2] += (p0 + p1) + (p2 + p3);
                    union { uint2 u; short4b s; } pv;
                    pv.u.x = pkbf(p0, p1);
                    pv.u.y = pkbf(p2, p3);
                    bp[qb2] = pv.s;
                }

                const int cc = 2 * w + (quad >> 1);
                const int sub = (quad & 1) * 4;
                #pragma unroll
                for (int db = 0; db < 4; ++db) {
                    int rv = db * 16 + col;
                    short4b av = *(const short4b*)(Vcur + ((size_t)rv * 8 + (cc ^ (rv & 7))) * 8 + sub);
                    #pragma unroll
                    for (int qb2 = 0; qb2 < 4; ++qb2)
                        o_[db][qb2] = __builtin_amdgcn_mfma_f32_16x16x16bf16_1k(
                            av, bp[qb2], o_[db][qb2], 0, 0, 0);
                }

                __syncthreads();
            }

            #pragma unroll
            for (int qb2 = 0; qb2 < 4; ++qb2) {
                lq[qb2] += __shfl_xor(lq[qb2], 16);
                lq[qb2] += __shfl_xor(lq[qb2], 32);
            }
            if (quad == 0) {
                #pragma unroll
                for (int qb2 = 0; qb2 < 4; ++qb2) Lred[w * 64 + qb2 * 16 + col] = lq[qb2];
            }
            {
                float* myreg = Ored + w * 4096;
                #pragma unroll
                for (int db = 0; db < 4; ++db)
                    #pragma unroll
                    for (int qb2 = 0; qb2 < 4; ++qb2) {
                        int q = qb2 * 16 + col;
                        int swch = (db * 4 + quad) ^ col;
                        *(floatx4*)(myreg + q * 64 + swch * 4) = o_[db][qb2];
                    }
            }
            __syncthreads();

            {
                const int qloc = w * 16 + (lane >> 2);
                float lsum = Lred[qloc] + Lred[64 + qloc] + Lred[128 + qloc] + Lred[192 + qloc];
                float linv = 1.f / lsum;
                const int dc0 = (lane & 3) * 4;
                floatx4 accv[4];
                #pragma unroll
                for (int j = 0; j < 4; ++j) {
                    int swch = (dc0 + j) ^ (qloc & 15);
                    const float* p = Ored + (size_t)qloc * 64 + swch * 4;
                    floatx4 a = *(const floatx4*)p;
                    a += *(const floatx4*)(p + 4096);
                    a += *(const floatx4*)(p + 8192);
                    a += *(const floatx4*)(p + 12288);
                    accv[j] = a;
                }
                const size_t rowb = ((size_t)(bi * SEQ + q0 + qloc)) * D_MODEL + hi * HDIM + dc0 * 4;
                uint4 u0, u1;
                u0.x = pkbf(accv[0][0] * linv, accv[0][1] * linv);
                u0.y = pkbf(accv[0][2] * linv, accv[0][3] * linv);
                u0.z = pkbf(accv[1][0] * linv, accv[1][1] * linv);
                u0.w = pkbf(accv[1][2] * linv, accv[1][3] * linv);
                u1.x = pkbf(accv[2][0] * linv, accv[2][1] * linv);
                u1.y = pkbf(accv[2][2] * linv, accv[2][3] * linv);
                u1.z = pkbf(accv[3][0] * linv, accv[3][1] * linv);
                u1.w = pkbf(accv[3][2] * linv, accv[3][3] * linv);
                *(uint4*)(Hb + rowb) = u0;
                *(uint4*)(Hb + rowb + 8) = u1;
            }
        }
    }

    grid_sync(bar);

    // ---------------- Phase D: out-projection, block tile 128x64 (512 blocks exact) --
    // 4 waves, wave tile 32x64.
    {
        ushort_t* As = (ushort_t*)smemf;            // [128][64] chunked, 16 KB
        ushort_t* Bs = (ushort_t*)smemf + 8192;     // [64][64]  chunked,  8 KB
        const int bm = blk >> 4, bn = blk & 15;
        const int m0 = bm * 128, n0 = bn * 64;

        floatx4 acc[2][4];
        #pragma unroll
        for (int i = 0; i < 2; ++i)
            #pragma unroll
            for (int j = 0; j < 4; ++j) acc[i][j] = zero;

        #pragma unroll 1
        for (int k0 = 0; k0 < KDIM; k0 += 64) {
            #pragma unroll
            for (int i = 0; i < 4; ++i) {
                int c = i * 256 + tid;
                int row = c >> 3;
                int kc = (c & 7) ^ (row & 7);
                glds16(Hb + (size_t)(m0 + row) * KDIM + k0 + kc * 8, As + (i * 256 + w * 64) * 8);
            }
            #pragma unroll
            for (int i = 0; i < 2; ++i) {
                int c = i * 256 + tid;
                int row = c >> 3;
                int kc = (c & 7) ^ (row & 7);
                glds16(WtO + (size_t)(n0 + row) * KDIM + k0 + kc * 8, Bs + (i * 256 + w * 64) * 8);
            }
            __syncthreads();
            #pragma unroll
            for (int ks = 0; ks < 2; ++ks) {
                short8 af[2], bfr[4];
                const int kc = ks * 4 + quad;
                #pragma unroll
                for (int mt = 0; mt < 2; ++mt) {
                    int r = w * 32 + mt * 16 + col;
                    af[mt] = *(const short8*)(As + ((size_t)r * 8 + (kc ^ (r & 7))) * 8);
                }
                #pragma unroll
                for (int nt = 0; nt < 4; ++nt) {
                    int r = nt * 16 + col;
                    bfr[nt] = *(const short8*)(Bs + ((size_t)r * 8 + (kc ^ (r & 7))) * 8);
                }
                #pragma unroll
                for (int mt = 0; mt < 2; ++mt)
                    #pragma unroll
                    for (int nt = 0; nt < 4; ++nt)
                        acc[mt][nt] = __builtin_amdgcn_mfma_f32_16x16x32_bf16(
                            af[mt], bfr[nt], acc[mt][nt], 0, 0, 0);
            }
            __syncthreads();
        }

        #pragma unroll
        for (int mt = 0; mt < 2; ++mt)
            #pragma unroll
            for (int nt = 0; nt < 4; ++nt) {
                int n = n0 + nt * 16 + col;
                float bb = bo[n];
                #pragma unroll
                for (int r = 0; r < 4; ++r) {
                    int m = m0 + w * 32 + mt * 16 + quad * 4 + r;
                    Cf[(size_t)m * D_MODEL + n] = acc[mt][nt][r] + bb;
                }
            }
    }
}

extern "C" void kernel_launch(void* const* d_in, const int* in_sizes, int n_in,
                              void* d_out, int out_size, void* d_ws, size_t ws_size,
                              hipStream_t stream)
{
    (void)in_sizes; (void)n_in; (void)out_size; (void)ws_size;
    const float* x  = (const float*)d_in[0];
    const float* Wq = (const float*)d_in[1];
    const float* bq = (const float*)d_in[2];
    const float* Wk = (const float*)d_in[3];
    const float* bk = (const float*)d_in[4];
    const float* Wv = (const float*)d_in[5];
    const float* bv = (const float*)d_in[6];
    const float* Wo = (const float*)d_in[7];
    const float* bo = (const float*)d_in[8];

    const size_t E = (size_t)MROWS * D_MODEL;
    ushort_t* xb    = (ushort_t*)d_ws;               // [4096][1024] bf16
    ushort_t* WtQKV = xb + E;                        // [3072][1024] bf16
    ushort_t* WtO   = WtQKV + 3 * (size_t)D_MODEL * KDIM;
    ushort_t* Qb    = WtO + (size_t)D_MODEL * KDIM;  // [b,h,s,d] bf16 (pre-scaled)
    ushort_t* Kb    = Qb + E;                        // [b,h,s,d] bf16
    ushort_t* Vb    = Kb + E;                        // [b,h,d,s] bf16 (transposed)
    ushort_t* Hb    = Vb + E;                        // [4096][1024] bf16
    unsigned* bar   = (unsigned*)(Hb + E);           // 8 B barrier state

    bar_init<<<1, 64, 0, stream>>>(bar);
    mega<<<dim3(NB), 256, 0, stream>>>(x, Wq, bq, Wk, bk, Wv, bv, Wo, bo,
                                       xb, WtQKV, WtO, Qb, Kb, Vb, Hb,
                                       (float*)d_out, bar);
}